// Round 16
// baseline (145.055 us; speedup 1.0000x reference)
//
#include <hip/hip_runtime.h>

#define T_SEQ 2048
#define DIM   768
#define NH    12
#define HD    64
#define KT    24     // k-tiles per fragment row (768/32)
#define TSZ   512    // elements per 16x32 fragment tile (64 lanes x 8)

typedef __attribute__((ext_vector_type(8))) short short8;
typedef __attribute__((ext_vector_type(4))) float floatx4;
typedef __attribute__((ext_vector_type(4))) unsigned short ushort4v;

#define MFMA16(a,b,c) __builtin_amdgcn_mfma_f32_16x16x32_bf16((a),(b),(c),0,0,0)

static __device__ __forceinline__ unsigned short f2bf(float f){
  union { float f; unsigned u; } v; v.f = f;
  unsigned r = v.u + 0x7fffu + ((v.u >> 16) & 1u);
  return (unsigned short)(r >> 16);
}
static __device__ __forceinline__ float bf2f(unsigned short u){
  union { unsigned u; float f; } v; v.u = ((unsigned)u) << 16;
  return v.f;
}

// ---------------- fp32 -> bf16 convert + fragment-major swizzle -------------
// Tile(r-tile, c-tile) of 16x32, lane-ordered: element (r,c) at
//   tile*512 + ((r&15) + 16*((c&31)>>3))*8 + (c&7)
// so an MFMA fragment load is base + tile*512 + lane*8 (contiguous 1KB/wave).
__global__ void convert_kernel(const float* __restrict__ x,
                               const float* __restrict__ wq,
                               const float* __restrict__ wk,
                               const float* __restrict__ wv,
                               const float* __restrict__ wp,
                               unsigned short* __restrict__ xb,
                               unsigned short* __restrict__ wqkvb,
                               unsigned short* __restrict__ wpb){
  const int stride = gridDim.x * blockDim.x;
  const int i0 = blockIdx.x * blockDim.x + threadIdx.x;
  const int XC = T_SEQ * 96;   // 8-elem chunks in x  (C/8 = 96)
  const int WC = DIM * 96;     // 8-elem chunks per weight matrix

  for (int f = i0; f < XC; f += stride){
    const int r = f / 96, kc = f - r*96;
    const float* s = x + (size_t)r*DIM + kc*8;
    short8 o;
    #pragma unroll
    for (int e=0;e<8;e++) o[e] = (short)f2bf(s[e]);
    *(short8*)(xb + (size_t)(((r>>4)*KT + (kc>>2))*TSZ
                  + ((r&15) + 16*(kc&3))*8)) = o;
  }
  for (int f = i0; f < WC; f += stride){
    const int r = f / 96, kc = f - r*96;
    const size_t dst = (size_t)(((r>>4)*KT + (kc>>2))*TSZ
                     + ((r&15) + 16*(kc&3))*8);
    const size_t src = (size_t)r*DIM + kc*8;
    short8 oq, ok, ov, op;
    #pragma unroll
    for (int e=0;e<8;e++){
      oq[e] = (short)f2bf(wq[src+e]);
      ok[e] = (short)f2bf(wk[src+e]);
      ov[e] = (short)f2bf(wv[src+e]);
      op[e] = (short)f2bf(wp[src+e]);
    }
    *(short8*)(wqkvb + dst)              = oq;
    *(short8*)(wqkvb + (size_t)DIM*DIM   + dst) = ok;
    *(short8*)(wqkvb + (size_t)2*DIM*DIM + dst) = ov;
    *(short8*)(wpb   + dst)              = op;
  }
}

// ---------------- QKV projection + lerp + rmsnorm + rope --------------------
// 2 waves per block, SAME 64x64 tile, split-K: wave w does kt in [12w,12w+12).
// Wave 1 publishes fp32 partials via LDS; wave 0 adds + epilogue.
// grid (32, 36): cb/12 = {q,k,v}, cb%12 = head.
__global__ __launch_bounds__(128) void qkv_kernel(
    const unsigned short* __restrict__ xb,
    const unsigned short* __restrict__ wqkvb,
    const float* __restrict__ vi,
    const float* __restrict__ lambp,
    unsigned short* __restrict__ qb,
    unsigned short* __restrict__ kb,
    unsigned short* __restrict__ vb){
  __shared__ float msh[64*68];   // 17408 B, stride 68 breaks conflicts
  const int w  = threadIdx.x >> 6;
  const int l  = threadIdx.x & 63;
  const int lr = l & 15, lq = l >> 4;
  const int rb = blockIdx.x, cb = blockIdx.y;
  const int mat = cb / NH, head = cb % NH;
  const int row0 = rb*64;

  floatx4 acc[4][4];
  #pragma unroll
  for (int i=0;i<4;i++)
    #pragma unroll
    for (int j=0;j<4;j++) acc[i][j] = (floatx4){0.f,0.f,0.f,0.f};

  const unsigned short* Ab = xb + (size_t)(rb*4)*KT*TSZ + l*8;
  const unsigned short* Bb = wqkvb + (size_t)mat*DIM*DIM
                           + (size_t)(head*4)*KT*TSZ + l*8;

  const int kt0 = w*12;
  short8 a[4], b[4];
  #pragma unroll
  for (int rt=0;rt<4;rt++) a[rt] = *(const short8*)(Ab + (size_t)(rt*KT + kt0)*TSZ);
  #pragma unroll
  for (int ct=0;ct<4;ct++) b[ct] = *(const short8*)(Bb + (size_t)(ct*KT + kt0)*TSZ);

  for (int i = 0; i < 12; i++){
    const int ktn = kt0 + ((i+1 < 12) ? (i+1) : 0);   // wrap: unconditional
    short8 an[4], bn[4];
    #pragma unroll
    for (int rt=0;rt<4;rt++) an[rt] = *(const short8*)(Ab + (size_t)(rt*KT+ktn)*TSZ);
    #pragma unroll
    for (int ct=0;ct<4;ct++) bn[ct] = *(const short8*)(Bb + (size_t)(ct*KT+ktn)*TSZ);
    #pragma unroll
    for (int rt=0;rt<4;rt++)
      #pragma unroll
      for (int ct=0;ct<4;ct++)
        acc[rt][ct] = MFMA16(a[rt], b[ct], acc[rt][ct]);
    #pragma unroll
    for (int rt=0;rt<4;rt++) a[rt] = an[rt];
    #pragma unroll
    for (int ct=0;ct<4;ct++) b[ct] = bn[ct];
  }

  // split-K merge: wave1 -> LDS, wave0 adds
  if (w == 1){
    #pragma unroll
    for (int rt=0;rt<4;rt++)
      #pragma unroll
      for (int ct=0;ct<4;ct++)
        *(floatx4*)&msh[(size_t)l*68 + (rt*4+ct)*4] = acc[rt][ct];
  }
  __syncthreads();
  if (w != 0) return;
  #pragma unroll
  for (int rt=0;rt<4;rt++)
    #pragma unroll
    for (int ct=0;ct<4;ct++){
      floatx4 t = *(const floatx4*)&msh[(size_t)l*68 + (rt*4+ct)*4];
      #pragma unroll
      for (int r=0;r<4;r++) acc[rt][ct][r] += t[r];
    }

  if (mat == 2){
    const float lamb = *lambp;
    unsigned short* Vh = vb + (size_t)head*T_SEQ*HD;
    #pragma unroll
    for (int rt=0;rt<4;rt++){
      const int tb = row0 + rt*16 + lq*4;    // key index base (4 keys)
      #pragma unroll
      for (int ct=0;ct<4;ct++){
        const int d = ct*16 + lr;
        ushort4v pk;
        #pragma unroll
        for (int r=0;r<4;r++){
          float vv = (1.0f - lamb)*acc[rt][ct][r]
                   + lamb * vi[(size_t)(tb + r)*DIM + head*HD + d];
          pk[r] = f2bf(vv);
        }
        *(ushort4v*)(Vh + (size_t)((tb>>5)*4 + ct)*TSZ
                        + (lr + 16*((tb&31)>>3))*8 + (tb&7)) = pk;
      }
    }
  } else {
    unsigned short* dst = (mat==0 ? qb : kb) + (size_t)head*T_SEQ*HD;
    #pragma unroll
    for (int rt=0;rt<4;rt++){
      float ss[4];
      #pragma unroll
      for (int r=0;r<4;r++)
        ss[r] = acc[rt][0][r]*acc[rt][0][r] + acc[rt][1][r]*acc[rt][1][r]
              + acc[rt][2][r]*acc[rt][2][r] + acc[rt][3][r]*acc[rt][3][r];
      #pragma unroll
      for (int mm=1; mm<16; mm<<=1){
        #pragma unroll
        for (int r=0;r<4;r++) ss[r] += __shfl_xor(ss[r], mm);
      }
      float scl[4];
      #pragma unroll
      for (int r=0;r<4;r++)
        scl[r] = rsqrtf(ss[r]*(1.0f/64.0f) + 1.1920929e-7f);

      #pragma unroll
      for (int ct=0;ct<2;ct++){
        const int i = ct*16 + lr;               // rope pair index 0..31
        const float inv = __expf(-(float)i * (9.210340371976184f/32.0f));
        const int lane8 = ((i>>3)&3)*16;        // 16*((i&31)>>3)
        #pragma unroll
        for (int r=0;r<4;r++){
          const int t = row0 + rt*16 + lq*4 + r;
          const float f = (float)t * inv;
          const float c = cosf(f), s = sinf(f);
          const float x1 = acc[rt][ct][r]*scl[r], x2 = acc[rt][ct+2][r]*scl[r];
          const size_t base = (size_t)((t>>4)*2)*TSZ
                            + ((t&15) + lane8)*8 + (i&7);
          dst[base]       = f2bf(x1*c + x2*s);   // col i   (dimtile 0)
          dst[base + TSZ] = f2bf(x2*c - x1*s);   // col i+32 (dimtile 1)
        }
      }
    }
  }
}

// ---------------- causal flash attention (fragment-major Q/K/V) -------------
// Fixed-max softmax; grid (64,12), 512 thr; balanced (127-bx, bx) pairing.
// Per iteration K and V reads are each one contiguous 4KB span.
__global__ __launch_bounds__(512) void attn_kernel(
    const unsigned short* __restrict__ qb,
    const unsigned short* __restrict__ kb,
    const unsigned short* __restrict__ vb,
    unsigned short* __restrict__ yb){   // swizzled fragment-major
  __shared__ unsigned short plds[8][16*40];
  __shared__ unsigned short Osh[8][64][20];
  __shared__ float lsh[8][16];
  const int w  = threadIdx.x >> 6;
  const int l  = threadIdx.x & 63;
  const int lr = l & 15, lq = l >> 4;
  const int head = blockIdx.y;

  const unsigned short* Q = qb + (size_t)head*T_SEQ*HD + l*8;
  const unsigned short* K = kb + (size_t)head*T_SEQ*HD + l*8;
  const unsigned short* V = vb + (size_t)head*T_SEQ*HD + l*8;

  #pragma unroll
  for (int ph = 0; ph < 2; ph++){
    const int qt = ph ? (int)blockIdx.x : (127 - (int)blockIdx.x);  // heavy first
    const int q0 = qt*16;

    const short8 qf0 = *(const short8*)(Q + (size_t)qt*1024);
    const short8 qf1 = *(const short8*)(Q + (size_t)qt*1024 + TSZ);

    floatx4 O[4];
    #pragma unroll
    for (int nt=0; nt<4; nt++) O[nt] = (floatx4){0.f,0.f,0.f,0.f};
    float lsum[4] = {0.f,0.f,0.f,0.f};

    const int ntile = (q0 + 15)/32 + 1;
    int kt = w;
    short8 kf0, kf1, kf2, kf3;
    if (kt < ntile){
      const unsigned short* kp = K + (size_t)kt*2048;
      kf0 = *(const short8*)kp;               kf1 = *(const short8*)(kp + TSZ);
      kf2 = *(const short8*)(kp + 2*TSZ);     kf3 = *(const short8*)(kp + 3*TSZ);
    }
    for (; kt < ntile; kt += 8){
      const int kbase = kt*32;
      const unsigned short* vp = V + (size_t)kt*2048;
      short8 vf[4];
      #pragma unroll
      for (int nt=0; nt<4; nt++)
        vf[nt] = *(const short8*)(vp + (size_t)nt*TSZ);

      floatx4 S0 = (floatx4){0.f,0.f,0.f,0.f};
      floatx4 S1 = (floatx4){0.f,0.f,0.f,0.f};
      S0 = MFMA16(qf0, kf0, S0);
      S0 = MFMA16(qf1, kf1, S0);
      S1 = MFMA16(qf0, kf2, S1);
      S1 = MFMA16(qf1, kf3, S1);

      const int ktn = kt + 8;
      if (ktn < ntile){
        const unsigned short* kp = K + (size_t)ktn*2048;
        kf0 = *(const short8*)kp;               kf1 = *(const short8*)(kp + TSZ);
        kf2 = *(const short8*)(kp + 2*TSZ);     kf3 = *(const short8*)(kp + 3*TSZ);
      }

      // p = exp(s - 8), s = S*0.125  =>  exp2(S*0.125*log2e - 8*log2e)
      float p0[4], p1[4];
      const int qr = q0 + lq*4;
      #pragma unroll
      for (int r=0; r<4; r++){
        float e0 = __builtin_amdgcn_exp2f(S0[r]*0.18033688011112043f - 11.541560327111707f);
        float e1 = __builtin_amdgcn_exp2f(S1[r]*0.18033688011112043f - 11.541560327111707f);
        p0[r] = (kbase + lr      > qr + r) ? 0.f : e0;
        p1[r] = (kbase + 16 + lr > qr + r) ? 0.f : e1;
        lsum[r] += p0[r] + p1[r];
      }

      // P: C-layout -> A-layout through per-wave LDS slab
      unsigned short* pl = &plds[w][0];
      #pragma unroll
      for (int r=0; r<4; r++){
        const int row = lq*4 + r;
        pl[row*40 + lr]      = f2bf(p0[r]);
        pl[row*40 + 16 + lr] = f2bf(p1[r]);
      }
      __asm__ volatile("s_waitcnt lgkmcnt(0)" ::: "memory");
      const short8 pf = *(const short8*)(pl + lr*40 + lq*8);

      #pragma unroll
      for (int nt=0; nt<4; nt++) O[nt] = MFMA16(pf, vf[nt], O[nt]);
    }

    #pragma unroll
    for (int mm=1; mm<16; mm<<=1){
      #pragma unroll
      for (int r=0; r<4; r++) lsum[r] += __shfl_xor(lsum[r], mm);
    }

    if (lr == 0){
      #pragma unroll
      for (int r=0; r<4; r++) lsh[w][lq*4+r] = lsum[r];
    }
    #pragma unroll
    for (int nt=0; nt<4; nt++){
      ushort4v pk;
      #pragma unroll
      for (int r=0; r<4; r++) pk[r] = f2bf(O[nt][r]);
      *(ushort4v*)&Osh[w][l][nt*4] = pk;
    }
    __syncthreads();

    if (w < 4){
      const int nt = w;
      float L[4] = {0.f,0.f,0.f,0.f};
      float Of[4] = {0.f,0.f,0.f,0.f};
      #pragma unroll
      for (int ww=0; ww<8; ww++){
        #pragma unroll
        for (int r=0; r<4; r++) L[r] += lsh[ww][lq*4+r];
        ushort4v pk = *(const ushort4v*)&Osh[ww][l][nt*4];
        #pragma unroll
        for (int r=0; r<4; r++) Of[r] += bf2f(pk[r]);
      }
      // swizzled store: row = q0+lq*4+r, col = head*64 + nt*16 + lr
      const int colt = head*2 + (nt >> 1);
      const int lane_hi = 16*((nt & 1)*2 + (lr >> 3));
      const size_t tbase = (size_t)(qt*KT + colt)*TSZ + (lr & 7);
      #pragma unroll
      for (int r=0; r<4; r++){
        yb[tbase + (size_t)((lq*4 + r) + lane_hi)*8] = f2bf(Of[r] / L[r]);
      }
    }
    __syncthreads();
  }
}

// ---------------- output projection (fp32 out, 2-wave split-K) --------------
// grid (32, 12), 128 threads; wave w does kt in [12w, 12w+12).
__global__ __launch_bounds__(128) void proj_kernel(
    const unsigned short* __restrict__ yb,
    const unsigned short* __restrict__ wpb,
    float* __restrict__ out){
  __shared__ float msh[64*68];
  const int w  = threadIdx.x >> 6;
  const int l  = threadIdx.x & 63;
  const int lr = l & 15, lq = l >> 4;
  const int rb = blockIdx.x, cb = blockIdx.y;
  const int row0 = rb*64, col0 = cb*64;

  floatx4 acc[4][4];
  #pragma unroll
  for (int i=0;i<4;i++)
    #pragma unroll
    for (int j=0;j<4;j++) acc[i][j] = (floatx4){0.f,0.f,0.f,0.f};

  const unsigned short* Ab = yb  + (size_t)(rb*4)*KT*TSZ + l*8;
  const unsigned short* Bb = wpb + (size_t)(cb*4)*KT*TSZ + l*8;

  const int kt0 = w*12;
  short8 a[4], b[4];
  #pragma unroll
  for (int rt=0;rt<4;rt++) a[rt] = *(const short8*)(Ab + (size_t)(rt*KT + kt0)*TSZ);
  #pragma unroll
  for (int ct=0;ct<4;ct++) b[ct] = *(const short8*)(Bb + (size_t)(ct*KT + kt0)*TSZ);

  for (int i = 0; i < 12; i++){
    const int ktn = kt0 + ((i+1 < 12) ? (i+1) : 0);
    short8 an[4], bn[4];
    #pragma unroll
    for (int rt=0;rt<4;rt++) an[rt] = *(const short8*)(Ab + (size_t)(rt*KT+ktn)*TSZ);
    #pragma unroll
    for (int ct=0;ct<4;ct++) bn[ct] = *(const short8*)(Bb + (size_t)(ct*KT+ktn)*TSZ);
    #pragma unroll
    for (int rt=0;rt<4;rt++)
      #pragma unroll
      for (int ct=0;ct<4;ct++)
        acc[rt][ct] = MFMA16(a[rt], b[ct], acc[rt][ct]);
    #pragma unroll
    for (int rt=0;rt<4;rt++) a[rt] = an[rt];
    #pragma unroll
    for (int ct=0;ct<4;ct++) b[ct] = bn[ct];
  }

  if (w == 1){
    #pragma unroll
    for (int rt=0;rt<4;rt++)
      #pragma unroll
      for (int ct=0;ct<4;ct++)
        *(floatx4*)&msh[(size_t)l*68 + (rt*4+ct)*4] = acc[rt][ct];
  }
  __syncthreads();
  if (w != 0) return;
  #pragma unroll
  for (int rt=0;rt<4;rt++)
    #pragma unroll
    for (int ct=0;ct<4;ct++){
      floatx4 t = *(const floatx4*)&msh[(size_t)l*68 + (rt*4+ct)*4];
      #pragma unroll
      for (int r=0;r<4;r++) acc[rt][ct][r] += t[r];
    }

  #pragma unroll
  for (int rt=0;rt<4;rt++){
    #pragma unroll
    for (int ct=0;ct<4;ct++){
      const int col = col0 + ct*16 + lr;
      #pragma unroll
      for (int r=0;r<4;r++){
        const int row = row0 + rt*16 + lq*4 + r;
        out[(size_t)row*DIM + col] = acc[rt][ct][r];
      }
    }
  }
}

extern "C" void kernel_launch(void* const* d_in, const int* in_sizes, int n_in,
                              void* d_out, int out_size, void* d_ws, size_t ws_size,
                              hipStream_t stream){
  const float* x   = (const float*)d_in[0];
  const float* vi  = (const float*)d_in[1];
  const float* Wq  = (const float*)d_in[2];
  const float* Wk  = (const float*)d_in[3];
  const float* Wv  = (const float*)d_in[4];
  const float* Wp  = (const float*)d_in[5];
  const float* lamb= (const float*)d_in[6];

  const size_t XN = (size_t)T_SEQ*DIM;   // 1572864
  const size_t WN = (size_t)DIM*DIM;     // 589824
  char* ws = (char*)d_ws;
  unsigned short* xb    = (unsigned short*)ws; ws += XN*2;
  unsigned short* wqkvb = (unsigned short*)ws; ws += 3*WN*2;
  unsigned short* wpb   = (unsigned short*)ws; ws += WN*2;
  unsigned short* qb    = (unsigned short*)ws; ws += XN*2;
  unsigned short* kb    = (unsigned short*)ws; ws += XN*2;
  unsigned short* vb    = (unsigned short*)ws; ws += XN*2;
  unsigned short* yb    = xb;  // alias: xb dead after qkv_kernel

  convert_kernel<<<1024, 256, 0, stream>>>(x, Wq, Wk, Wv, Wp, xb, wqkvb, wpb);
  qkv_kernel<<<dim3(32,36), 128, 0, stream>>>(xb, wqkvb, vi, lamb, qb, kb, vb);
  attn_kernel<<<dim3(64,12), 512, 0, stream>>>(qb, kb, vb, yb);
  proj_kernel<<<dim3(32,12), 128, 0, stream>>>(yb, wpb, (float*)d_out);
}

// Round 17
// 139.371 us; speedup vs baseline: 1.0408x; 1.0408x over previous
//
#include <hip/hip_runtime.h>

#define T_SEQ 2048
#define DIM   768
#define NH    12
#define HD    64
#define KT    24     // k-tiles per fragment row (768/32)
#define TSZ   512    // elements per 16x32 fragment tile (64 lanes x 8)

typedef __attribute__((ext_vector_type(8))) short short8;
typedef __attribute__((ext_vector_type(4))) float floatx4;
typedef __attribute__((ext_vector_type(4))) unsigned short ushort4v;

#define MFMA16(a,b,c) __builtin_amdgcn_mfma_f32_16x16x32_bf16((a),(b),(c),0,0,0)

static __device__ __forceinline__ unsigned short f2bf(float f){
  union { float f; unsigned u; } v; v.f = f;
  unsigned r = v.u + 0x7fffu + ((v.u >> 16) & 1u);
  return (unsigned short)(r >> 16);
}
static __device__ __forceinline__ float bf2f(unsigned short u){
  union { unsigned u; float f; } v; v.u = ((unsigned)u) << 16;
  return v.f;
}

// ---------------- fp32 -> bf16 convert + fragment-major swizzle -------------
__global__ void convert_kernel(const float* __restrict__ x,
                               const float* __restrict__ wq,
                               const float* __restrict__ wk,
                               const float* __restrict__ wv,
                               const float* __restrict__ wp,
                               unsigned short* __restrict__ xb,
                               unsigned short* __restrict__ wqkvb,
                               unsigned short* __restrict__ wpb){
  const int stride = gridDim.x * blockDim.x;
  const int i0 = blockIdx.x * blockDim.x + threadIdx.x;
  const int XC = T_SEQ * 96;
  const int WC = DIM * 96;

  for (int f = i0; f < XC; f += stride){
    const int r = f / 96, kc = f - r*96;
    const float* s = x + (size_t)r*DIM + kc*8;
    short8 o;
    #pragma unroll
    for (int e=0;e<8;e++) o[e] = (short)f2bf(s[e]);
    *(short8*)(xb + (size_t)(((r>>4)*KT + (kc>>2))*TSZ
                  + ((r&15) + 16*(kc&3))*8)) = o;
  }
  for (int f = i0; f < WC; f += stride){
    const int r = f / 96, kc = f - r*96;
    const size_t dst = (size_t)(((r>>4)*KT + (kc>>2))*TSZ
                     + ((r&15) + 16*(kc&3))*8);
    const size_t src = (size_t)r*DIM + kc*8;
    short8 oq, ok, ov, op;
    #pragma unroll
    for (int e=0;e<8;e++){
      oq[e] = (short)f2bf(wq[src+e]);
      ok[e] = (short)f2bf(wk[src+e]);
      ov[e] = (short)f2bf(wv[src+e]);
      op[e] = (short)f2bf(wp[src+e]);
    }
    *(short8*)(wqkvb + dst)              = oq;
    *(short8*)(wqkvb + (size_t)DIM*DIM   + dst) = ok;
    *(short8*)(wqkvb + (size_t)2*DIM*DIM + dst) = ov;
    *(short8*)(wpb   + dst)              = op;
  }
}

// ---------------- QKV projection + lerp + rmsnorm + rope (r15) --------------
__global__ __launch_bounds__(64) void qkv_kernel(
    const unsigned short* __restrict__ xb,
    const unsigned short* __restrict__ wqkvb,
    const float* __restrict__ vi,
    const float* __restrict__ lambp,
    unsigned short* __restrict__ qb,
    unsigned short* __restrict__ kb,
    unsigned short* __restrict__ vb){
  const int l  = threadIdx.x;
  const int lr = l & 15, lq = l >> 4;
  const int rb = blockIdx.x, cb = blockIdx.y;
  const int mat = cb / NH, head = cb % NH;
  const int row0 = rb*64;

  floatx4 acc[4][4];
  #pragma unroll
  for (int i=0;i<4;i++)
    #pragma unroll
    for (int j=0;j<4;j++) acc[i][j] = (floatx4){0.f,0.f,0.f,0.f};

  const unsigned short* Ab = xb + (size_t)(rb*4)*KT*TSZ + l*8;
  const unsigned short* Bb = wqkvb + (size_t)mat*DIM*DIM
                           + (size_t)(head*4)*KT*TSZ + l*8;

  short8 a[4], b[4];
  #pragma unroll
  for (int rt=0;rt<4;rt++) a[rt] = *(const short8*)(Ab + (size_t)rt*KT*TSZ);
  #pragma unroll
  for (int ct=0;ct<4;ct++) b[ct] = *(const short8*)(Bb + (size_t)ct*KT*TSZ);

  for (int kt = 0; kt < KT; kt++){
    const int ktn = (kt + 1 < KT) ? kt + 1 : 0;
    short8 an[4], bn[4];
    #pragma unroll
    for (int rt=0;rt<4;rt++) an[rt] = *(const short8*)(Ab + (size_t)(rt*KT+ktn)*TSZ);
    #pragma unroll
    for (int ct=0;ct<4;ct++) bn[ct] = *(const short8*)(Bb + (size_t)(ct*KT+ktn)*TSZ);
    #pragma unroll
    for (int rt=0;rt<4;rt++)
      #pragma unroll
      for (int ct=0;ct<4;ct++)
        acc[rt][ct] = MFMA16(a[rt], b[ct], acc[rt][ct]);
    #pragma unroll
    for (int rt=0;rt<4;rt++) a[rt] = an[rt];
    #pragma unroll
    for (int ct=0;ct<4;ct++) b[ct] = bn[ct];
  }

  if (mat == 2){
    const float lamb = *lambp;
    unsigned short* Vh = vb + (size_t)head*T_SEQ*HD;
    #pragma unroll
    for (int rt=0;rt<4;rt++){
      const int tb = row0 + rt*16 + lq*4;
      #pragma unroll
      for (int ct=0;ct<4;ct++){
        const int d = ct*16 + lr;
        ushort4v pk;
        #pragma unroll
        for (int r=0;r<4;r++){
          float vv = (1.0f - lamb)*acc[rt][ct][r]
                   + lamb * vi[(size_t)(tb + r)*DIM + head*HD + d];
          pk[r] = f2bf(vv);
        }
        *(ushort4v*)(Vh + (size_t)((tb>>5)*4 + ct)*TSZ
                        + (lr + 16*((tb&31)>>3))*8 + (tb&7)) = pk;
      }
    }
  } else {
    unsigned short* dst = (mat==0 ? qb : kb) + (size_t)head*T_SEQ*HD;
    #pragma unroll
    for (int rt=0;rt<4;rt++){
      float ss[4];
      #pragma unroll
      for (int r=0;r<4;r++)
        ss[r] = acc[rt][0][r]*acc[rt][0][r] + acc[rt][1][r]*acc[rt][1][r]
              + acc[rt][2][r]*acc[rt][2][r] + acc[rt][3][r]*acc[rt][3][r];
      #pragma unroll
      for (int mm=1; mm<16; mm<<=1){
        #pragma unroll
        for (int r=0;r<4;r++) ss[r] += __shfl_xor(ss[r], mm);
      }
      float scl[4];
      #pragma unroll
      for (int r=0;r<4;r++)
        scl[r] = rsqrtf(ss[r]*(1.0f/64.0f) + 1.1920929e-7f);

      #pragma unroll
      for (int ct=0;ct<2;ct++){
        const int i = ct*16 + lr;
        const float inv = __expf(-(float)i * (9.210340371976184f/32.0f));
        const int lane8 = ((i>>3)&3)*16;
        #pragma unroll
        for (int r=0;r<4;r++){
          const int t = row0 + rt*16 + lq*4 + r;
          const float f = (float)t * inv;
          const float c = cosf(f), s = sinf(f);
          const float x1 = acc[rt][ct][r]*scl[r], x2 = acc[rt][ct+2][r]*scl[r];
          const size_t base = (size_t)((t>>4)*2)*TSZ
                            + ((t&15) + lane8)*8 + (i&7);
          dst[base]       = f2bf(x1*c + x2*s);
          dst[base + TSZ] = f2bf(x2*c - x1*s);
        }
      }
    }
  }
}

// ---------------- causal flash attention: 32-row superblock per wave --------
// Fixed-max softmax; grid (32,12), 512 thr = 8 waves; balanced (63-bx, bx)
// phase pairing. Each wave holds TWO q-tiles (32 rows): per key-tile
// iteration the same 8KB of K/V feeds 16 MFMAs (2x reuse vs r15).
// LDS: per-wave P slabs (20.5KB) overlay the Osh partial region (barrier-
// separated). All 8 waves merge (one (q-half, dim-tile) each).
__global__ __launch_bounds__(512, 4) void attn_kernel(
    const unsigned short* __restrict__ qb,
    const unsigned short* __restrict__ kb,
    const unsigned short* __restrict__ vb,
    unsigned short* __restrict__ yb){   // swizzled fragment-major
  __shared__ __align__(16) char smem[8*64*40*2 + 8*32*4];  // Osh 40960 + lsh 1024
  unsigned short* Osh = (unsigned short*)smem;             // [8][64][40]
  float* lsh = (float*)(smem + 40960);                     // [8][32]

  const int w  = threadIdx.x >> 6;
  const int l  = threadIdx.x & 63;
  const int lr = l & 15, lq = l >> 4;
  const int head = blockIdx.y;

  const unsigned short* Q = qb + (size_t)head*T_SEQ*HD + l*8;
  const unsigned short* K = kb + (size_t)head*T_SEQ*HD + l*8;
  const unsigned short* V = vb + (size_t)head*T_SEQ*HD + l*8;

  #pragma unroll
  for (int ph = 0; ph < 2; ph++){
    const int qs = ph ? (int)blockIdx.x : (63 - (int)blockIdx.x);  // heavy first
    const int q0 = qs*32;

    const short8 qf00 = *(const short8*)(Q + (size_t)(qs*2)*1024);
    const short8 qf01 = *(const short8*)(Q + (size_t)(qs*2)*1024 + TSZ);
    const short8 qf10 = *(const short8*)(Q + (size_t)(qs*2+1)*1024);
    const short8 qf11 = *(const short8*)(Q + (size_t)(qs*2+1)*1024 + TSZ);

    floatx4 O0[4], O1[4];
    #pragma unroll
    for (int nt=0; nt<4; nt++){
      O0[nt] = (floatx4){0.f,0.f,0.f,0.f};
      O1[nt] = (floatx4){0.f,0.f,0.f,0.f};
    }
    float ls0[4] = {0.f,0.f,0.f,0.f}, ls1[4] = {0.f,0.f,0.f,0.f};

    const int ntile = qs + 1;
    for (int kt = w; kt < ntile; kt += 8){
      const int kbase = kt*32;
      const unsigned short* kp = K + (size_t)kt*2048;
      const unsigned short* vp = V + (size_t)kt*2048;
      short8 vf[4];
      #pragma unroll
      for (int nt=0; nt<4; nt++) vf[nt] = *(const short8*)(vp + (size_t)nt*TSZ);
      const short8 kf0 = *(const short8*)kp;
      const short8 kf1 = *(const short8*)(kp + TSZ);
      const short8 kf2 = *(const short8*)(kp + 2*TSZ);
      const short8 kf3 = *(const short8*)(kp + 3*TSZ);

      floatx4 S00 = (floatx4){0.f,0.f,0.f,0.f};
      floatx4 S01 = (floatx4){0.f,0.f,0.f,0.f};
      floatx4 S10 = (floatx4){0.f,0.f,0.f,0.f};
      floatx4 S11 = (floatx4){0.f,0.f,0.f,0.f};
      S00 = MFMA16(qf00, kf0, S00);  S00 = MFMA16(qf01, kf1, S00);
      S01 = MFMA16(qf00, kf2, S01);  S01 = MFMA16(qf01, kf3, S01);
      S10 = MFMA16(qf10, kf0, S10);  S10 = MFMA16(qf11, kf1, S10);
      S11 = MFMA16(qf10, kf2, S11);  S11 = MFMA16(qf11, kf3, S11);

      // p = exp(s - 8), s = S*0.125  =>  exp2(S*0.125*log2e - 8*log2e)
      float p00[4], p01[4], p10[4], p11[4];
      const int qrA = q0 + lq*4;
      const int qrB = q0 + 16 + lq*4;
      #pragma unroll
      for (int r=0; r<4; r++){
        float e00 = __builtin_amdgcn_exp2f(S00[r]*0.18033688011112043f - 11.541560327111707f);
        float e01 = __builtin_amdgcn_exp2f(S01[r]*0.18033688011112043f - 11.541560327111707f);
        float e10 = __builtin_amdgcn_exp2f(S10[r]*0.18033688011112043f - 11.541560327111707f);
        float e11 = __builtin_amdgcn_exp2f(S11[r]*0.18033688011112043f - 11.541560327111707f);
        p00[r] = (kbase + lr      > qrA + r) ? 0.f : e00;
        p01[r] = (kbase + 16 + lr > qrA + r) ? 0.f : e01;
        p10[r] = (kbase + lr      > qrB + r) ? 0.f : e10;
        p11[r] = (kbase + 16 + lr > qrB + r) ? 0.f : e11;
        ls0[r] += p00[r] + p01[r];
        ls1[r] += p10[r] + p11[r];
      }

      // two P transposes through the per-wave LDS slab (overlays Osh)
      unsigned short* pl = (unsigned short*)smem + w*1280;
      #pragma unroll
      for (int r=0; r<4; r++){
        const int row = lq*4 + r;
        pl[row*40 + lr]            = f2bf(p00[r]);
        pl[row*40 + 16 + lr]       = f2bf(p01[r]);
        pl[640 + row*40 + lr]      = f2bf(p10[r]);
        pl[640 + row*40 + 16 + lr] = f2bf(p11[r]);
      }
      __asm__ volatile("s_waitcnt lgkmcnt(0)" ::: "memory");
      const short8 pf0 = *(const short8*)(pl + lr*40 + lq*8);
      const short8 pf1 = *(const short8*)(pl + 640 + lr*40 + lq*8);

      #pragma unroll
      for (int nt=0; nt<4; nt++) O0[nt] = MFMA16(pf0, vf[nt], O0[nt]);
      #pragma unroll
      for (int nt=0; nt<4; nt++) O1[nt] = MFMA16(pf1, vf[nt], O1[nt]);
    }

    #pragma unroll
    for (int mm=1; mm<16; mm<<=1){
      #pragma unroll
      for (int r=0; r<4; r++){
        ls0[r] += __shfl_xor(ls0[r], mm);
        ls1[r] += __shfl_xor(ls1[r], mm);
      }
    }

    __syncthreads();   // all waves done with P slabs before Osh overlay

    if (lr == 0){
      #pragma unroll
      for (int r=0; r<4; r++){
        lsh[w*32 + lq*4 + r]      = ls0[r];
        lsh[w*32 + 16 + lq*4 + r] = ls1[r];
      }
    }
    #pragma unroll
    for (int nt=0; nt<4; nt++){
      ushort4v pk0, pk1;
      #pragma unroll
      for (int r=0; r<4; r++){ pk0[r] = f2bf(O0[nt][r]); pk1[r] = f2bf(O1[nt][r]); }
      *(ushort4v*)&Osh[((size_t)w*64 + l)*40 + nt*4]      = pk0;
      *(ushort4v*)&Osh[((size_t)w*64 + l)*40 + 16 + nt*4] = pk1;
    }
    __syncthreads();

    // merge: wave w handles (q-half = w>>2, dim-tile = w&3)
    {
      const int qh = w >> 2, nt = w & 3;
      float L[4] = {0.f,0.f,0.f,0.f};
      float Of[4] = {0.f,0.f,0.f,0.f};
      #pragma unroll
      for (int ww=0; ww<8; ww++){
        #pragma unroll
        for (int r=0; r<4; r++) L[r] += lsh[ww*32 + qh*16 + lq*4 + r];
        ushort4v pk = *(const ushort4v*)&Osh[((size_t)ww*64 + l)*40 + qh*16 + nt*4];
        #pragma unroll
        for (int r=0; r<4; r++) Of[r] += bf2f(pk[r]);
      }
      const int qt = qs*2 + qh;
      const int colt = head*2 + (nt >> 1);
      const int lane_hi = 16*((nt & 1)*2 + (lr >> 3));
      const size_t tbase = (size_t)(qt*KT + colt)*TSZ + (lr & 7);
      #pragma unroll
      for (int r=0; r<4; r++){
        yb[tbase + (size_t)((lq*4 + r) + lane_hi)*8] = f2bf(Of[r] / L[r]);
      }
    }
    __syncthreads();   // protect overlay before next phase's P slabs
  }
}

// ---------------- output projection (fp32 out, r15 single-wave) -------------
__global__ __launch_bounds__(64) void proj_kernel(
    const unsigned short* __restrict__ yb,
    const unsigned short* __restrict__ wpb,
    float* __restrict__ out){
  const int l  = threadIdx.x;
  const int lr = l & 15, lq = l >> 4;
  const int rb = blockIdx.x, cb = blockIdx.y;
  const int row0 = rb*64, col0 = cb*64;

  floatx4 acc[4][4];
  #pragma unroll
  for (int i=0;i<4;i++)
    #pragma unroll
    for (int j=0;j<4;j++) acc[i][j] = (floatx4){0.f,0.f,0.f,0.f};

  const unsigned short* Ab = yb  + (size_t)(rb*4)*KT*TSZ + l*8;
  const unsigned short* Bb = wpb + (size_t)(cb*4)*KT*TSZ + l*8;

  short8 a[4], b[4];
  #pragma unroll
  for (int rt=0;rt<4;rt++) a[rt] = *(const short8*)(Ab + (size_t)rt*KT*TSZ);
  #pragma unroll
  for (int ct=0;ct<4;ct++) b[ct] = *(const short8*)(Bb + (size_t)ct*KT*TSZ);

  for (int kt = 0; kt < KT; kt++){
    const int ktn = (kt + 1 < KT) ? kt + 1 : 0;
    short8 an[4], bn[4];
    #pragma unroll
    for (int rt=0;rt<4;rt++) an[rt] = *(const short8*)(Ab + (size_t)(rt*KT+ktn)*TSZ);
    #pragma unroll
    for (int ct=0;ct<4;ct++) bn[ct] = *(const short8*)(Bb + (size_t)(ct*KT+ktn)*TSZ);
    #pragma unroll
    for (int rt=0;rt<4;rt++)
      #pragma unroll
      for (int ct=0;ct<4;ct++)
        acc[rt][ct] = MFMA16(a[rt], b[ct], acc[rt][ct]);
    #pragma unroll
    for (int rt=0;rt<4;rt++) a[rt] = an[rt];
    #pragma unroll
    for (int ct=0;ct<4;ct++) b[ct] = bn[ct];
  }

  #pragma unroll
  for (int rt=0;rt<4;rt++){
    #pragma unroll
    for (int ct=0;ct<4;ct++){
      const int col = col0 + ct*16 + lr;
      #pragma unroll
      for (int r=0;r<4;r++){
        const int row = row0 + rt*16 + lq*4 + r;
        out[(size_t)row*DIM + col] = acc[rt][ct][r];
      }
    }
  }
}

extern "C" void kernel_launch(void* const* d_in, const int* in_sizes, int n_in,
                              void* d_out, int out_size, void* d_ws, size_t ws_size,
                              hipStream_t stream){
  const float* x   = (const float*)d_in[0];
  const float* vi  = (const float*)d_in[1];
  const float* Wq  = (const float*)d_in[2];
  const float* Wk  = (const float*)d_in[3];
  const float* Wv  = (const float*)d_in[4];
  const float* Wp  = (const float*)d_in[5];
  const float* lamb= (const float*)d_in[6];

  const size_t XN = (size_t)T_SEQ*DIM;   // 1572864
  const size_t WN = (size_t)DIM*DIM;     // 589824
  char* ws = (char*)d_ws;
  unsigned short* xb    = (unsigned short*)ws; ws += XN*2;
  unsigned short* wqkvb = (unsigned short*)ws; ws += 3*WN*2;
  unsigned short* wpb   = (unsigned short*)ws; ws += WN*2;
  unsigned short* qb    = (unsigned short*)ws; ws += XN*2;
  unsigned short* kb    = (unsigned short*)ws; ws += XN*2;
  unsigned short* vb    = (unsigned short*)ws; ws += XN*2;
  unsigned short* yb    = xb;  // alias: xb dead after qkv_kernel

  convert_kernel<<<1024, 256, 0, stream>>>(x, Wq, Wk, Wv, Wp, xb, wqkvb, wpb);
  qkv_kernel<<<dim3(32,36), 64, 0, stream>>>(xb, wqkvb, vi, lamb, qb, kb, vb);
  attn_kernel<<<dim3(32,12), 512, 0, stream>>>(qb, kb, vb, yb);
  proj_kernel<<<dim3(32,12), 64, 0, stream>>>(yb, wpb, (float*)d_out);
}